// Round 1
// baseline (453.301 us; speedup 1.0000x reference)
//
#include <hip/hip_runtime.h>

// Problem constants (fixed by reference)
#define DB 8
#define DT 4096
#define DC 1024
#define GM (DB*DT)   // 32768
#define GN (2*DC)    // 2048 (state cols 0..1023, gate cols 1024..2047)
#define GK DC        // 1024

// Segmented-scan parameters
#define SEG 64       // segment length (outputs per worker) -> 32 waves/CU
#define NSEG (DT/SEG)
#define WU 64        // warmup steps (contraction ~0.55/step kills s0 error)
#define UCH 8        // prefetch chunk (small: keep VGPRs < 128, no spill)

typedef _Float16 f16;
typedef _Float16 f16x8 __attribute__((ext_vector_type(8)));
typedef _Float16 f16x4 __attribute__((ext_vector_type(4)));
typedef float    f32x4 __attribute__((ext_vector_type(4)));

__device__ __forceinline__ void async_copy16(const void* g, void* l) {
    __builtin_amdgcn_global_load_lds((const __attribute__((address_space(1))) void*)g,
                                     (__attribute__((address_space(3))) void*)l,
                                     16, 0, 0);
}

// ---- fp32 -> f16 conversion of x -------------------------------------------
__global__ __launch_bounds__(256) void conv_x_kernel(const float* __restrict__ x,
                                                     f16* __restrict__ xh) {
    const size_t i = (size_t)blockIdx.x * 256 + threadIdx.x;
    const f32x4 v = *(const f32x4*)(x + 4*i);
    f16x4 h; h.x = (f16)v.x; h.y = (f16)v.y; h.z = (f16)v.z; h.w = (f16)v.w;
    *(f16x4*)(xh + 4*i) = h;
}

// ---- fp32 -> f16 of [W_state; W_gate] as one [2048,1024] row-major matrix --
__global__ __launch_bounds__(256) void conv_w_kernel(const float* __restrict__ Ws,
                                                     const float* __restrict__ Wg,
                                                     f16* __restrict__ wc) {
    const int i = blockIdx.x * 256 + threadIdx.x;
    const int e = i * 4;
    const int n = e >> 10;
    const int k = e & 1023;
    const float* src = (n < DC) ? (Ws + (size_t)n * DC + k)
                                : (Wg + (size_t)(n - DC) * DC + k);
    const f32x4 v = *(const f32x4*)src;
    f16x4 h; h.x = (f16)v.x; h.y = (f16)v.y; h.z = (f16)v.z; h.w = (f16)v.w;
    *(f16x4*)(wc + e) = h;
}

// ============================================================================
// Fused GEMM: [32768,1024] x [2048,1024]^T, bias + (sigmoid for gate).
// 256x256 tile, BK=64, 8 waves (2Mx4N), 8-phase counted-vmcnt schedule
// (T2+T3+T4+T5). Per wave: 128x64 output as acc[8][4] f32x4; m-frag t owns
// C rows (2t+wm)*16, n-frag u owns C cols (4u+wn)*16, so phase (mq,nq)
// consumes CONTIGUOUS 128-row LDS regions: A rows [mq*128,+128), B rows
// [nq*128,+128). Stage unit = one such 16KB region = 2 global_load_lds/thread.
//
// LDS: 2 K-tile slots (even/odd kt), each A[256][64]+B[256][64] f16 = 128KB.
// XOR-8 chunk swizzle (phys chunk = logical ^ (row&7)) via pre-swizzled
// GLOBAL source (gload_lds dest must be linear); ds_read applies same XOR.
//
// Phase table per iter j (computes kt=2j from slot0 in ph1-4, kt=2j+1 from
// slot1 in ph5-8); stage target's last reader is always <= previous phase,
// and both vmcnt(4) points (ph4, ph8) cover every landing deadline:
//   ph1 (s0,mq0,nq0)  stage s1.A-R1 <- 2j+1
//   ph2 (s0,mq0,nq1)  stage s1.B-S1 <- 2j+1
//   ph3 (s0,mq1,nq0)  stage s0.A-R0 <- 2j+2
//   ph4 (s0,mq1,nq1)  stage s0.B-S0 <- 2j+2   vmcnt(4)
//   ph5 (s1,mq0,nq0)  stage s0.A-R1 <- 2j+2
//   ph6 (s1,mq0,nq1)  stage s0.B-S1 <- 2j+2
//   ph7 (s1,mq1,nq0)  stage s1.A-R0 <- 2j+3
//   ph8 (s1,mq1,nq1)  stage s1.B-S0 <- 2j+3   vmcnt(4)
// Last iter clamps 2j+2/2j+3 to 15 (dummy restage, never read). Raw
// s_barrier (no implicit vmcnt(0) drain) + compiler memory fences.
// ============================================================================
__device__ __forceinline__ void stage2(const f16* sb, f16* lb, int rowoff,
                                       int kt, int wave) {
    // sb already includes (tile_row + wave*8 + (lane>>3))*GK + swz_chunk*8
    const size_t so = (size_t)rowoff * GK + (size_t)kt * 64;
    f16* d = lb + rowoff * 64 + wave * 512;          // wave-uniform dest
    async_copy16(sb + so, d);                         // rows [rowoff, +64)
    async_copy16(sb + so + (size_t)64 * GK, d + 4096);// rows [rowoff+64, +64)
}

template<int MQ, int NQ, bool VM>
__device__ __forceinline__ void phase(const f16* As, const f16* Bs,
        f32x4 (&acc)[8][4], const int abase, const int bbase,
        const int (&ksc)[2],
        const f16* sSrc, f16* sDst, const int srow, const int kt,
        const int wave) {
    f16x8 af[4][2], bf[2][2];
#pragma unroll
    for (int t = 0; t < 4; ++t)
#pragma unroll
        for (int ks = 0; ks < 2; ++ks)
            af[t][ks] = *(const f16x8*)&As[(MQ*4 + t)*2048 + abase + ksc[ks]];
#pragma unroll
    for (int u = 0; u < 2; ++u)
#pragma unroll
        for (int ks = 0; ks < 2; ++ks)
            bf[u][ks] = *(const f16x8*)&Bs[(NQ*2 + u)*4096 + bbase + ksc[ks]];
    stage2(sSrc, sDst, srow, kt, wave);
    asm volatile("" ::: "memory");
    __builtin_amdgcn_s_barrier();
    asm volatile("s_waitcnt lgkmcnt(0)" ::: "memory");
    __builtin_amdgcn_sched_barrier(0);               // rule 18: pin MFMA after wait
    __builtin_amdgcn_s_setprio(1);                   // T5
#pragma unroll
    for (int ks = 0; ks < 2; ++ks)
#pragma unroll
        for (int t = 0; t < 4; ++t)
#pragma unroll
            for (int u = 0; u < 2; ++u)
                acc[MQ*4 + t][NQ*2 + u] = __builtin_amdgcn_mfma_f32_16x16x32_f16(
                    af[t][ks], bf[u][ks], acc[MQ*4 + t][NQ*2 + u], 0, 0, 0);
    __builtin_amdgcn_s_setprio(0);
    if constexpr (VM)
        asm volatile("s_waitcnt vmcnt(4)" ::: "memory");  // counted, never 0
    asm volatile("" ::: "memory");
    __builtin_amdgcn_s_barrier();
}

__global__ __launch_bounds__(512, 2) void gemm_kernel(
        const f16* __restrict__ xh, const f16* __restrict__ wc,
        const float* __restrict__ b_state, const float* __restrict__ b_gate,
        f16* __restrict__ pxh, f16* __restrict__ gh) {
    __shared__ f16 lds_a[2][16384];   // [slot][256 rows][64], swizzled chunks
    __shared__ f16 lds_b[2][16384];

    const int tid  = threadIdx.x;
    const int lane = tid & 63;
    const int wave = tid >> 6;        // 0..7

    // Bijective XCD swizzle (nwg=1024 % 8 == 0): XCD x gets bm in [x*16,+16),
    // bn fastest -> B panel (4MB) resident in that XCD's L2; A tile reused by
    // 8 consecutive blocks.
    const int wg = (blockIdx.x & 7) * 128 + (blockIdx.x >> 3);
    const int bm = wg >> 3;           // 0..127
    const int bn = wg & 7;            // 0..7

    const int lr = lane & 15, lq = lane >> 4;
    const int wm = wave & 1,  wn = wave >> 1;   // 2 x 4 wave grid
    const int abase = (wm*16 + lr) * 64;        // f16 units
    const int bbase = (wn*16 + lr) * 64;
    const int ksc[2] = { ((0*4 + lq) ^ (lr & 7)) * 8,
                         ((1*4 + lq) ^ (lr & 7)) * 8 };

    // Pre-swizzled global staging source: lane -> row +(lane>>3),
    // logical chunk (lane&7)^((lane>>3)&7) lands at linear phys chunk lane&7.
    const int rl = lane >> 3;                   // 0..7
    const int chs = (lane & 7) ^ rl;
    const f16* aSrc = xh + (size_t)(bm*256 + wave*8 + rl) * GK + chs*8;
    const f16* bSrc = wc + (size_t)(bn*256 + wave*8 + rl) * GK + chs*8;

    f32x4 acc[8][4] = {};

    // Prologue: K0 fully, K1's R0/S0 (12 loads); vmcnt(4) leaves K1's 2 units
    // in flight -> identical to steady-state ph8 exit.
    stage2(aSrc, lds_a[0], 0,   0, wave);
    stage2(bSrc, lds_b[0], 0,   0, wave);
    stage2(aSrc, lds_a[0], 128, 0, wave);
    stage2(bSrc, lds_b[0], 128, 0, wave);
    stage2(aSrc, lds_a[1], 0,   1, wave);
    stage2(bSrc, lds_b[1], 0,   1, wave);
    asm volatile("s_waitcnt vmcnt(4)" ::: "memory");
    asm volatile("" ::: "memory");
    __builtin_amdgcn_s_barrier();
    asm volatile("" ::: "memory");

#pragma unroll 1
    for (int j = 0; j < 8; ++j) {
        const int k1 = 2*j + 1;
        const int ka = (j < 7) ? 2*j + 2 : 15;   // clamped dummy on last iter
        const int kb = (j < 7) ? 2*j + 3 : 15;
        phase<0,0,false>(lds_a[0], lds_b[0], acc, abase, bbase, ksc, aSrc, lds_a[1], 128, k1, wave);
        phase<0,1,false>(lds_a[0], lds_b[0], acc, abase, bbase, ksc, bSrc, lds_b[1], 128, k1, wave);
        phase<1,0,false>(lds_a[0], lds_b[0], acc, abase, bbase, ksc, aSrc, lds_a[0], 0,   ka, wave);
        phase<1,1,true >(lds_a[0], lds_b[0], acc, abase, bbase, ksc, bSrc, lds_b[0], 0,   ka, wave);
        phase<0,0,false>(lds_a[1], lds_b[1], acc, abase, bbase, ksc, aSrc, lds_a[0], 128, ka, wave);
        phase<0,1,false>(lds_a[1], lds_b[1], acc, abase, bbase, ksc, bSrc, lds_b[0], 128, ka, wave);
        phase<1,0,false>(lds_a[1], lds_b[1], acc, abase, bbase, ksc, aSrc, lds_a[1], 0,   kb, wave);
        phase<1,1,true >(lds_a[1], lds_b[1], acc, abase, bbase, ksc, bSrc, lds_b[1], 0,   kb, wave);
    }

    // Don't exit/overlap epilogue with LDS-writing loads still in flight.
    asm volatile("s_waitcnt vmcnt(0)" ::: "memory");

    // Epilogue. D layout: col = lane&15, row = (lane>>4)*4 + reg (m89).
    const int r0 = lq * 4;
    if (bn < 4) {
#pragma unroll
        for (int u = 0; u < 4; ++u) {
            const int gcol = bn*256 + (u*4 + wn)*16 + lr;
            const float bias = b_state[gcol];
#pragma unroll
            for (int t = 0; t < 8; ++t) {
                const int grow = bm*256 + (2*t + wm)*16 + r0;
#pragma unroll
                for (int r = 0; r < 4; ++r)
                    pxh[(size_t)(grow + r) * DC + gcol] = (f16)(acc[t][u][r] + bias);
            }
        }
    } else {
#pragma unroll
        for (int u = 0; u < 4; ++u) {
            const int gcol = (bn - 4)*256 + (u*4 + wn)*16 + lr;
            const float bias = b_gate[gcol];
#pragma unroll
            for (int t = 0; t < 8; ++t) {
                const int grow = bm*256 + (2*t + wm)*16 + r0;
#pragma unroll
                for (int r = 0; r < 4; ++r) {
                    const float v = acc[t][u][r] + bias;
                    gh[(size_t)(grow + r) * DC + gcol] = (f16)(1.0f / (1.0f + __expf(-v)));
                }
            }
        }
    }
}

// ---- segmented scan over T: s = tanh(p_t + s); out = g_t * s ---------------
// 8192 chains x 64 segments of 64 steps; each segment (except first) warms up
// 64 steps from s=0 (error decays by prod(1-tanh^2) ~ e^-38 typical).
// tanh(z) = 1 - 2/(1+2^(L*z)), L = 2*log2(e); track sL = L*s so the dependent
// chain is fma->exp2->add->rcp->fma. UCH=8 keeps live registers ~70 (< 128
// cap at 4 waves/EU): round-1's 315us was scratch spill from U=32 arrays.
__global__ __launch_bounds__(256, 4) void scan_kernel(
        const f16* __restrict__ ph, const f16* __restrict__ gh,
        float* __restrict__ out) {
    const int tau   = blockIdx.x * 256 + threadIdx.x;   // 0..524287
    const int seg   = tau >> 13;                        // 0..63 (wave-uniform)
    const int chain = tau & 8191;
    const size_t base = (size_t)(chain >> 10) * ((size_t)DT * DC) + (chain & 1023);
    const float L = 2.8853900817779268f;                // 2*log2(e)
    float sL = 0.0f, s = 0.0f;
    const int t0 = seg * SEG;

    if (seg) {  // warmup: p only, no g, no stores
        const int tw = t0 - WU;
        f16 wA[UCH], wB[UCH];
        #pragma unroll
        for (int i = 0; i < UCH; ++i) wA[i] = ph[base + (size_t)(tw + i) * DC];
        #pragma unroll 1
        for (int ch = 0; ch < WU / UCH; ++ch) {
            #pragma unroll
            for (int i = 0; i < UCH; ++i)   // last iter reads t0..t0+7: valid
                wB[i] = ph[base + (size_t)(tw + (ch + 1) * UCH + i) * DC];
            #pragma unroll
            for (int i = 0; i < UCH; ++i) {
                const float u = fmaf((float)wA[i], L, sL);
                const float e = __builtin_amdgcn_exp2f(u);
                const float r = __builtin_amdgcn_rcpf(e + 1.0f);
                sL = fmaf(-2.0f * L, r, L);
            }
            #pragma unroll
            for (int i = 0; i < UCH; ++i) wA[i] = wB[i];
        }
    }

    float pA[UCH], pB[UCH], gA[UCH], gB[UCH];
    #pragma unroll
    for (int i = 0; i < UCH; ++i) {
        const size_t idx = base + (size_t)(t0 + i) * DC;
        pA[i] = (float)ph[idx] * L;
        gA[i] = (float)gh[idx];
    }
    #pragma unroll 1
    for (int ch = 0; ch < SEG / UCH; ++ch) {
        // Unconditional next-chunk prefetch (ph/gh padded by 16 steps, so
        // segment 63's final prefetch at t=4096..4103 stays in bounds).
        #pragma unroll
        for (int i = 0; i < UCH; ++i) {
            const size_t idx = base + (size_t)(t0 + (ch + 1) * UCH + i) * DC;
            pB[i] = (float)ph[idx] * L;
            gB[i] = (float)gh[idx];
        }
        #pragma unroll
        for (int i = 0; i < UCH; ++i) {
            const float u = pA[i] + sL;
            const float e = __builtin_amdgcn_exp2f(u);
            const float r = __builtin_amdgcn_rcpf(e + 1.0f);
            s  = fmaf(-2.0f, r, 1.0f);
            sL = fmaf(-2.0f * L, r, L);
            out[base + (size_t)(t0 + ch * UCH + i) * DC] = gA[i] * s;
        }
        #pragma unroll
        for (int i = 0; i < UCH; ++i) { pA[i] = pB[i]; gA[i] = gB[i]; }
    }
    if (seg == NSEG - 1) out[(size_t)DB * DT * DC + chain] = s;  // final_state
}

extern "C" void kernel_launch(void* const* d_in, const int* in_sizes, int n_in,
                              void* d_out, int out_size, void* d_ws, size_t ws_size,
                              hipStream_t stream) {
    const float* x  = (const float*)d_in[0];
    const float* Ws = (const float*)d_in[1];
    const float* bs = (const float*)d_in[2];
    const float* Wg = (const float*)d_in[3];
    const float* bg = (const float*)d_in[4];
    float* out = (float*)d_out;

    // workspace layout (~196 MiB):
    //   xh  f16[32768][1024], wc f16[2048][1024],
    //   pxh f16[32768+16][1024], gh f16[32768+16][1024]
    char* ws = (char*)d_ws;
    const size_t SZ_XH  = (size_t)GM * GK * 2;
    const size_t SZ_WC  = (size_t)GN * GK * 2;
    const size_t SZ_PXH = ((size_t)GM + 16) * DC * 2;
    f16* xh  = (f16*)ws;
    f16* wc  = (f16*)(ws + SZ_XH);
    f16* pxh = (f16*)(ws + SZ_XH + SZ_WC);
    f16* gh  = (f16*)(ws + SZ_XH + SZ_WC + SZ_PXH);

    conv_x_kernel<<<dim3(GM * GK / 1024), dim3(256), 0, stream>>>(x, xh);
    conv_w_kernel<<<dim3(GN * GK / 1024), dim3(256), 0, stream>>>(Ws, Wg, wc);
    gemm_kernel<<<dim3(1024), dim3(512), 0, stream>>>(xh, wc, bs, bg, pxh, gh);
    scan_kernel<<<dim3(DB * DC * NSEG / 256), dim3(256), 0, stream>>>(pxh, gh, out);
}

// Round 3
// 428.035 us; speedup vs baseline: 1.0590x; 1.0590x over previous
//
#include <hip/hip_runtime.h>

// Problem constants (fixed by reference)
#define DB 8
#define DT 4096
#define DC 1024
#define GM (DB*DT)   // 32768
#define GN (2*DC)    // 2048 (state cols 0..1023, gate cols 1024..2047)
#define GK DC        // 1024

// Segmented-scan parameters
#define SEG 64       // segment length (outputs per worker) -> 32 waves/CU
#define NSEG (DT/SEG)
#define WU 64        // warmup steps (contraction ~0.55/step kills s0 error)
#define UCH 8        // prefetch chunk (small: keep VGPRs < 128, no spill)

typedef _Float16 f16;
typedef _Float16 f16x8 __attribute__((ext_vector_type(8)));
typedef _Float16 f16x4 __attribute__((ext_vector_type(4)));
typedef float    f32x4 __attribute__((ext_vector_type(4)));

__device__ __forceinline__ void async_copy16(const void* g, void* l) {
    __builtin_amdgcn_global_load_lds((const __attribute__((address_space(1))) void*)g,
                                     (__attribute__((address_space(3))) void*)l,
                                     16, 0, 0);
}

// ---- fp32 -> f16 conversion of x -------------------------------------------
__global__ __launch_bounds__(256) void conv_x_kernel(const float* __restrict__ x,
                                                     f16* __restrict__ xh) {
    const size_t i = (size_t)blockIdx.x * 256 + threadIdx.x;
    const f32x4 v = *(const f32x4*)(x + 4*i);
    f16x4 h; h.x = (f16)v.x; h.y = (f16)v.y; h.z = (f16)v.z; h.w = (f16)v.w;
    *(f16x4*)(xh + 4*i) = h;
}

// ---- fp32 -> f16 of [W_state; W_gate] as one [2048,1024] row-major matrix --
__global__ __launch_bounds__(256) void conv_w_kernel(const float* __restrict__ Ws,
                                                     const float* __restrict__ Wg,
                                                     f16* __restrict__ wc) {
    const int i = blockIdx.x * 256 + threadIdx.x;
    const int e = i * 4;
    const int n = e >> 10;
    const int k = e & 1023;
    const float* src = (n < DC) ? (Ws + (size_t)n * DC + k)
                                : (Wg + (size_t)(n - DC) * DC + k);
    const f32x4 v = *(const f32x4*)src;
    f16x4 h; h.x = (f16)v.x; h.y = (f16)v.y; h.z = (f16)v.z; h.w = (f16)v.w;
    *(f16x4*)(wc + e) = h;
}

// ============================================================================
// Fused GEMM: [32768,1024] x [2048,1024]^T, bias + (sigmoid for gate).
// 256x256 tile, BK=64, 8 waves (2Mx4N), 8-phase counted-vmcnt schedule.
// RESUBMIT of round-2 (container flake, no measurement). Round-2 fix vs
// round-1: FULL fragment reuse across phases (round-1 re-read frags per
// quadrant: 48 ds_read_b128/K-tile/wave = LDS-BW-bound, 3000+ cyc LDS vs
// 2483 cyc MFMA per CU per K-tile). Now 24 reads/K-tile/wave:
//   P1 (mq0 x n01): read af<-A-R0 (8) + bfL<-B-S0 (4)
//   P2 (mq0 x n23): read bfH<-B-S1 (4)        [af reused]
//   P3 (mq1 x n01): read af<-A-R1 (8)         [bfL reused]
//   P4 (mq1 x n23): none                      [af, bfH reused]
// -> 192 KiB LDS reads/CU/K-tile ~1536-2260 cyc < 2483 cyc MFMA.
//
// LDS: 2 K-tile slots (even/odd kt), each A[256][64]+B[256][64] f16 = 128KB.
// XOR-8 chunk swizzle (phys chunk = logical ^ (row&7)) via pre-swizzled
// GLOBAL source (gload_lds dest must be linear); ds_read applies same XOR.
// Reads are b128-conflict-floor (8 lanes per chunk-group over 32 banks).
//
// Staging schedule per iter j (computes kt=2j from slot0 in P1-4, kt=2j+1
// from slot1 in P5-8); every staged region's last ds_read is >=1 barrier
// earlier; vmcnt(4) at ph4/ph8 covers every landing deadline (verified by
// issue-order accounting: at P4's vmcnt(4) P1/P2's units landed; at P8's
// vmcnt(4) P3..P6's landed; each region staged >=4 phases before read):
//   ph1 stage s1.A-R1 <- 2j+1   ph5 stage s0.A-R1 <- 2j+2
//   ph2 stage s1.B-S1 <- 2j+1   ph6 stage s0.B-S1 <- 2j+2
//   ph3 stage s0.A-R0 <- 2j+2   ph7 stage s1.A-R0 <- 2j+3
//   ph4 stage s0.B-S0 <- 2j+2   ph8 stage s1.B-S0 <- 2j+3
//        vmcnt(4)                    vmcnt(4)
// Last iter clamps prefetch kt to 15 (dummy restage, never read). Raw
// s_barrier (no implicit vmcnt(0) drain); lgkmcnt(0)+sched_barrier(0)
// before each MFMA cluster (rule 18); setprio(1) around MFMA (T5).
// ============================================================================
__device__ __forceinline__ void stage2(const f16* sb, f16* lb, int rowoff,
                                       int kt, int wave) {
    // sb already includes (tile_row + wave*8 + (lane>>3))*GK + swz_chunk*8
    const size_t so = (size_t)rowoff * GK + (size_t)kt * 64;
    f16* d = lb + rowoff * 64 + wave * 512;          // wave-uniform dest
    async_copy16(sb + so, d);                         // rows [rowoff, +64)
    async_copy16(sb + so + (size_t)64 * GK, d + 4096);// rows [rowoff+64, +64)
}

template<bool RDA, int RDB, int MQ, int NQ, bool VM>
__device__ __forceinline__ void phase(const f16* As, const f16* Bs,
        f32x4 (&acc)[8][4], f16x8 (&af)[4][2], f16x8 (&bfL)[2][2],
        f16x8 (&bfH)[2][2], const int abase, const int bbase,
        const int (&ksc)[2], const f16* sSrc, f16* sDst, const int srow,
        const int kt, const int wave) {
    if constexpr (RDA) {
#pragma unroll
        for (int t = 0; t < 4; ++t)
#pragma unroll
            for (int ks = 0; ks < 2; ++ks)
                af[t][ks] = *(const f16x8*)&As[(MQ*4 + t)*2048 + abase + ksc[ks]];
    }
    if constexpr (RDB == 1) {
#pragma unroll
        for (int u = 0; u < 2; ++u)
#pragma unroll
            for (int ks = 0; ks < 2; ++ks)
                bfL[u][ks] = *(const f16x8*)&Bs[u*4096 + bbase + ksc[ks]];
    }
    if constexpr (RDB == 2) {
#pragma unroll
        for (int u = 0; u < 2; ++u)
#pragma unroll
            for (int ks = 0; ks < 2; ++ks)
                bfH[u][ks] = *(const f16x8*)&Bs[8192 + u*4096 + bbase + ksc[ks]];
    }
    stage2(sSrc, sDst, srow, kt, wave);
    asm volatile("" ::: "memory");
    __builtin_amdgcn_s_barrier();
    asm volatile("s_waitcnt lgkmcnt(0)" ::: "memory");
    __builtin_amdgcn_sched_barrier(0);               // rule 18: pin MFMA after wait
    __builtin_amdgcn_s_setprio(1);                   // T5
#pragma unroll
    for (int ks = 0; ks < 2; ++ks)
#pragma unroll
        for (int t = 0; t < 4; ++t)
#pragma unroll
            for (int u = 0; u < 2; ++u) {
                const f16x8 b = (NQ == 0) ? bfL[u][ks] : bfH[u][ks];
                acc[MQ*4 + t][NQ*2 + u] = __builtin_amdgcn_mfma_f32_16x16x32_f16(
                    af[t][ks], b, acc[MQ*4 + t][NQ*2 + u], 0, 0, 0);
            }
    __builtin_amdgcn_s_setprio(0);
    if constexpr (VM)
        asm volatile("s_waitcnt vmcnt(4)" ::: "memory");  // counted, never 0
    asm volatile("" ::: "memory");
    __builtin_amdgcn_s_barrier();
}

__global__ __launch_bounds__(512, 2) void gemm_kernel(
        const f16* __restrict__ xh, const f16* __restrict__ wc,
        const float* __restrict__ b_state, const float* __restrict__ b_gate,
        f16* __restrict__ pxh, f16* __restrict__ gh) {
    __shared__ f16 lds_a[2][16384];   // [slot][256 rows][64], swizzled chunks
    __shared__ f16 lds_b[2][16384];

    const int tid  = threadIdx.x;
    const int lane = tid & 63;
    const int wave = tid >> 6;        // 0..7

    // Bijective XCD swizzle (nwg=1024 % 8 == 0): XCD x gets bm in [x*16,+16),
    // bn fastest -> B panel (4MB) resident in that XCD's L2; A tile reused by
    // 8 consecutive blocks.
    const int wg = (blockIdx.x & 7) * 128 + (blockIdx.x >> 3);
    const int bm = wg >> 3;           // 0..127
    const int bn = wg & 7;            // 0..7

    const int lr = lane & 15, lq = lane >> 4;
    const int wm = wave & 1,  wn = wave >> 1;   // 2 x 4 wave grid
    const int abase = (wm*16 + lr) * 64;        // f16 units
    const int bbase = (wn*16 + lr) * 64;
    const int ksc[2] = { ((0*4 + lq) ^ (lr & 7)) * 8,
                         ((1*4 + lq) ^ (lr & 7)) * 8 };

    // Pre-swizzled global staging source: lane -> row +(lane>>3),
    // logical chunk (lane&7)^((lane>>3)&7) lands at linear phys chunk lane&7.
    const int rl = lane >> 3;                   // 0..7
    const int chs = (lane & 7) ^ rl;
    const f16* aSrc = xh + (size_t)(bm*256 + wave*8 + rl) * GK + chs*8;
    const f16* bSrc = wc + (size_t)(bn*256 + wave*8 + rl) * GK + chs*8;

    f32x4 acc[8][4] = {};
    f16x8 af[4][2], bfL[2][2], bfH[2][2];

    // Prologue: K0 fully, K1's R0/S0 (12 loads); vmcnt(4) leaves K1's 2 units
    // in flight -> identical to steady-state ph8 exit.
    stage2(aSrc, lds_a[0], 0,   0, wave);
    stage2(bSrc, lds_b[0], 0,   0, wave);
    stage2(aSrc, lds_a[0], 128, 0, wave);
    stage2(bSrc, lds_b[0], 128, 0, wave);
    stage2(aSrc, lds_a[1], 0,   1, wave);
    stage2(bSrc, lds_b[1], 0,   1, wave);
    asm volatile("s_waitcnt vmcnt(4)" ::: "memory");
    asm volatile("" ::: "memory");
    __builtin_amdgcn_s_barrier();
    asm volatile("" ::: "memory");

#pragma unroll 1
    for (int j = 0; j < 8; ++j) {
        const int k1 = 2*j + 1;
        const int ka = (j < 7) ? 2*j + 2 : 15;   // clamped dummy on last iter
        const int kb = (j < 7) ? 2*j + 3 : 15;
        phase<true, 1, 0, 0, false>(lds_a[0], lds_b[0], acc, af, bfL, bfH, abase, bbase, ksc, aSrc, lds_a[1], 128, k1, wave);
        phase<false,2, 0, 1, false>(lds_a[0], lds_b[0], acc, af, bfL, bfH, abase, bbase, ksc, bSrc, lds_b[1], 128, k1, wave);
        phase<true, 0, 1, 0, false>(lds_a[0], lds_b[0], acc, af, bfL, bfH, abase, bbase, ksc, aSrc, lds_a[0], 0,   ka, wave);
        phase<false,0, 1, 1, true >(lds_a[0], lds_b[0], acc, af, bfL, bfH, abase, bbase, ksc, bSrc, lds_b[0], 0,   ka, wave);
        phase<true, 1, 0, 0, false>(lds_a[1], lds_b[1], acc, af, bfL, bfH, abase, bbase, ksc, aSrc, lds_a[0], 128, ka, wave);
        phase<false,2, 0, 1, false>(lds_a[1], lds_b[1], acc, af, bfL, bfH, abase, bbase, ksc, bSrc, lds_b[0], 128, ka, wave);
        phase<true, 0, 1, 0, false>(lds_a[1], lds_b[1], acc, af, bfL, bfH, abase, bbase, ksc, aSrc, lds_a[1], 0,   kb, wave);
        phase<false,0, 1, 1, true >(lds_a[1], lds_b[1], acc, af, bfL, bfH, abase, bbase, ksc, bSrc, lds_b[1], 0,   kb, wave);
    }

    // Don't exit/overlap epilogue with LDS-writing loads still in flight.
    asm volatile("s_waitcnt vmcnt(0)" ::: "memory");

    // Epilogue. D layout: col = lane&15, row = (lane>>4)*4 + reg (m89).
    const int r0 = lq * 4;
    if (bn < 4) {
#pragma unroll
        for (int u = 0; u < 4; ++u) {
            const int gcol = bn*256 + (u*4 + wn)*16 + lr;
            const float bias = b_state[gcol];
#pragma unroll
            for (int t = 0; t < 8; ++t) {
                const int grow = bm*256 + (2*t + wm)*16 + r0;
#pragma unroll
                for (int r = 0; r < 4; ++r)
                    pxh[(size_t)(grow + r) * DC + gcol] = (f16)(acc[t][u][r] + bias);
            }
        }
    } else {
#pragma unroll
        for (int u = 0; u < 4; ++u) {
            const int gcol = (bn - 4)*256 + (u*4 + wn)*16 + lr;
            const float bias = b_gate[gcol];
#pragma unroll
            for (int t = 0; t < 8; ++t) {
                const int grow = bm*256 + (2*t + wm)*16 + r0;
#pragma unroll
                for (int r = 0; r < 4; ++r) {
                    const float v = acc[t][u][r] + bias;
                    gh[(size_t)(grow + r) * DC + gcol] = (f16)(1.0f / (1.0f + __expf(-v)));
                }
            }
        }
    }
}

// ---- segmented scan over T: s = tanh(p_t + s); out = g_t * s ---------------
// 8192 chains x 64 segments of 64 steps; each segment (except first) warms up
// 64 steps from s=0 (error decays by prod(1-tanh^2) ~ e^-38 typical).
// tanh(z) = 1 - 2/(1+2^(L*z)), L = 2*log2(e); track sL = L*s so the dependent
// chain is fma->exp2->add->rcp->fma. UCH=8 keeps live registers ~70 (< 128
// cap at 4 waves/EU): round-1's 315us was scratch spill from U=32 arrays.
__global__ __launch_bounds__(256, 4) void scan_kernel(
        const f16* __restrict__ ph, const f16* __restrict__ gh,
        float* __restrict__ out) {
    const int tau   = blockIdx.x * 256 + threadIdx.x;   // 0..524287
    const int seg   = tau >> 13;                        // 0..63 (wave-uniform)
    const int chain = tau & 8191;
    const size_t base = (size_t)(chain >> 10) * ((size_t)DT * DC) + (chain & 1023);
    const float L = 2.8853900817779268f;                // 2*log2(e)
    float sL = 0.0f, s = 0.0f;
    const int t0 = seg * SEG;

    if (seg) {  // warmup: p only, no g, no stores
        const int tw = t0 - WU;
        f16 wA[UCH], wB[UCH];
        #pragma unroll
        for (int i = 0; i < UCH; ++i) wA[i] = ph[base + (size_t)(tw + i) * DC];
        #pragma unroll 1
        for (int ch = 0; ch < WU / UCH; ++ch) {
            #pragma unroll
            for (int i = 0; i < UCH; ++i)   // last iter reads t0..t0+7: valid
                wB[i] = ph[base + (size_t)(tw + (ch + 1) * UCH + i) * DC];
            #pragma unroll
            for (int i = 0; i < UCH; ++i) {
                const float u = fmaf((float)wA[i], L, sL);
                const float e = __builtin_amdgcn_exp2f(u);
                const float r = __builtin_amdgcn_rcpf(e + 1.0f);
                sL = fmaf(-2.0f * L, r, L);
            }
            #pragma unroll
            for (int i = 0; i < UCH; ++i) wA[i] = wB[i];
        }
    }

    float pA[UCH], pB[UCH], gA[UCH], gB[UCH];
    #pragma unroll
    for (int i = 0; i < UCH; ++i) {
        const size_t idx = base + (size_t)(t0 + i) * DC;
        pA[i] = (float)ph[idx] * L;
        gA[i] = (float)gh[idx];
    }
    #pragma unroll 1
    for (int ch = 0; ch < SEG / UCH; ++ch) {
        // Unconditional next-chunk prefetch (ph/gh padded by 16 steps, so
        // segment 63's final prefetch at t=4096..4103 stays in bounds).
        #pragma unroll
        for (int i = 0; i < UCH; ++i) {
            const size_t idx = base + (size_t)(t0 + (ch + 1) * UCH + i) * DC;
            pB[i] = (float)ph[idx] * L;
            gB[i] = (float)gh[idx];
        }
        #pragma unroll
        for (int i = 0; i < UCH; ++i) {
            const float u = pA[i] + sL;
            const float e = __builtin_amdgcn_exp2f(u);
            const float r = __builtin_amdgcn_rcpf(e + 1.0f);
            s  = fmaf(-2.0f, r, 1.0f);
            sL = fmaf(-2.0f * L, r, L);
            out[base + (size_t)(t0 + ch * UCH + i) * DC] = gA[i] * s;
        }
        #pragma unroll
        for (int i = 0; i < UCH; ++i) { pA[i] = pB[i]; gA[i] = gB[i]; }
    }
    if (seg == NSEG - 1) out[(size_t)DB * DT * DC + chain] = s;  // final_state
}

extern "C" void kernel_launch(void* const* d_in, const int* in_sizes, int n_in,
                              void* d_out, int out_size, void* d_ws, size_t ws_size,
                              hipStream_t stream) {
    const float* x  = (const float*)d_in[0];
    const float* Ws = (const float*)d_in[1];
    const float* bs = (const float*)d_in[2];
    const float* Wg = (const float*)d_in[3];
    const float* bg = (const float*)d_in[4];
    float* out = (float*)d_out;

    // workspace layout (~196 MiB):
    //   xh  f16[32768][1024], wc f16[2048][1024],
    //   pxh f16[32768+16][1024], gh f16[32768+16][1024]
    char* ws = (char*)d_ws;
    const size_t SZ_XH  = (size_t)GM * GK * 2;
    const size_t SZ_WC  = (size_t)GN * GK * 2;
    const size_t SZ_PXH = ((size_t)GM + 16) * DC * 2;
    f16* xh  = (f16*)ws;
    f16* wc  = (f16*)(ws + SZ_XH);
    f16* pxh = (f16*)(ws + SZ_XH + SZ_WC);
    f16* gh  = (f16*)(ws + SZ_XH + SZ_WC + SZ_PXH);

    conv_x_kernel<<<dim3(GM * GK / 1024), dim3(256), 0, stream>>>(x, xh);
    conv_w_kernel<<<dim3(GN * GK / 1024), dim3(256), 0, stream>>>(Ws, Wg, wc);
    gemm_kernel<<<dim3(1024), dim3(512), 0, stream>>>(xh, wc, bs, bg, pxh, gh);
    scan_kernel<<<dim3(DB * DC * NSEG / 256), dim3(256), 0, stream>>>(pxh, gh, out);
}